// Round 1
// baseline (11200.178 us; speedup 1.0000x reference)
//
#include <hip/hip_runtime.h>

typedef float f32x4 __attribute__((ext_vector_type(4)));
typedef short s16x8 __attribute__((ext_vector_type(8)));
typedef unsigned short u16;
typedef unsigned short u16x4 __attribute__((ext_vector_type(4)));
typedef unsigned short u16x8 __attribute__((ext_vector_type(8)));

__device__ __forceinline__ float bf2f(u16 u){ union{unsigned int i; float f;} v; v.i=((unsigned int)u)<<16; return v.f; }
__device__ __forceinline__ u16 f2bf(float f){ union{float f; unsigned int i;} v; v.f=f; return (u16)((v.i + 0x7FFFu + ((v.i>>16)&1u))>>16); }

__device__ __forceinline__ void gld16(const void* gp, void* lp){
  __builtin_amdgcn_global_load_lds((__attribute__((address_space(1))) void*)(void*)gp,
                                   (__attribute__((address_space(3))) void*)lp, 16, 0, 0);
}

// ---------------- embed gather: x[r,:] = embed[ids[r],:] (fp32) ----------------
__global__ __launch_bounds__(256) void k_embed(const int* __restrict__ ids, const float* __restrict__ emb, float* __restrict__ x){
  int r = blockIdx.x;
  int id = ids[r];
  const f32x4* src = (const f32x4*)(emb + (size_t)id*1536);
  f32x4* dst = (f32x4*)(x + (size_t)r*1536);
  for (int i = threadIdx.x; i < 384; i += 256) dst[i] = src[i];
}

// ---------------- RMSNorm: h = bf16(x * rsqrt(mean(x^2)+eps) * w) ----------------
__global__ __launch_bounds__(256) void k_rms(const float* __restrict__ x, const float* __restrict__ w, u16* __restrict__ h){
  int r = blockIdx.x, tid = threadIdx.x;
  const f32x4* xr = (const f32x4*)(x + (size_t)r*1536);
  f32x4 v0 = xr[tid];
  float ss = v0.x*v0.x + v0.y*v0.y + v0.z*v0.z + v0.w*v0.w;
  f32x4 v1 = {0,0,0,0};
  if (tid < 128){ v1 = xr[256+tid]; ss += v1.x*v1.x + v1.y*v1.y + v1.z*v1.z + v1.w*v1.w; }
  #pragma unroll
  for (int off=32; off; off>>=1) ss += __shfl_xor(ss, off, 64);
  __shared__ float red[4];
  if ((tid&63)==0) red[tid>>6] = ss;
  __syncthreads();
  float tot = red[0]+red[1]+red[2]+red[3];
  float invr = rsqrtf(tot*(1.f/1536.f) + 1e-6f);
  const f32x4* w4 = (const f32x4*)w;
  u16x4* h4 = (u16x4*)(h + (size_t)r*1536);
  {
    f32x4 wv = w4[tid];
    u16x4 o; o.x=f2bf(v0.x*invr*wv.x); o.y=f2bf(v0.y*invr*wv.y); o.z=f2bf(v0.z*invr*wv.z); o.w=f2bf(v0.w*invr*wv.w);
    h4[tid] = o;
  }
  if (tid < 128){
    f32x4 wv = w4[256+tid];
    u16x4 o; o.x=f2bf(v1.x*invr*wv.x); o.y=f2bf(v1.y*invr*wv.y); o.z=f2bf(v1.z*invr*wv.z); o.w=f2bf(v1.w*invr*wv.w);
    h4[256+tid] = o;
  }
}

// ---------------- transpose+convert one 64x64 tile: src(K,N) fp32 -> dst(N,K) bf16 ----------------
// mode 0: dst row = roff + n ; mode 1 (gate): ((n>>4)<<5)+(n&15) ; mode 2 (up): +16
__device__ __forceinline__ void cvt_tile(const float* src, int K, int N, u16* dst, int k0, int n0, int roff, int mode){
  __shared__ float T[64*72];
  int tid = threadIdx.x;
  #pragma unroll
  for (int j=0;j<4;++j){
    int i = tid + j*256;
    int row = i>>4, nf = i&15;
    f32x4 vv = *(const f32x4*)(src + (size_t)(k0+row)*N + n0 + nf*4);
    *(f32x4*)&T[row*72 + nf*4] = vv;
  }
  __syncthreads();
  #pragma unroll
  for (int j=0;j<2;++j){
    int i = tid + j*256;
    int n = i>>3, kc = i&7;
    u16x8 o;
    #pragma unroll
    for (int m=0;m<8;++m) o[m] = f2bf(T[(kc*8+m)*72 + n]);
    int gn = n0 + n;
    int dr = (mode==0) ? (roff + gn) : (((gn>>4)<<5) + ((mode==2)?16:0) + (gn&15));
    *(u16x8*)(dst + (size_t)dr*K + k0 + kc*8) = o;
  }
}

__global__ __launch_bounds__(256) void k_cvt_layer(
  const float* __restrict__ Wq, const float* __restrict__ Wk, const float* __restrict__ Wv,
  const float* __restrict__ Wo, const float* __restrict__ Wg, const float* __restrict__ Wu,
  const float* __restrict__ Wd, u16* qkvt, u16* wot, u16* gut, u16* wdt)
{
  const float* src; int K, N; u16* dst; int roff=0, mode=0;
  switch (blockIdx.y){
    case 0: src=Wq; K=1536; N=1536; dst=qkvt; break;
    case 1: src=Wk; K=1536; N=256;  dst=qkvt; roff=1536; break;
    case 2: src=Wv; K=1536; N=256;  dst=qkvt; roff=1792; break;
    case 3: src=Wo; K=1536; N=1536; dst=wot;  break;
    case 4: src=Wg; K=1536; N=8960; dst=gut;  mode=1; break;
    case 5: src=Wu; K=1536; N=8960; dst=gut;  mode=2; break;
    default: src=Wd; K=8960; N=1536; dst=wdt; break;
  }
  int ntn = N>>6;
  int nt = (K>>6)*ntn;
  int t = blockIdx.x;
  if (t >= nt) return;
  cvt_tile(src, K, N, dst, (t/ntn)<<6, (t%ntn)<<6, roff, mode);
}

__global__ __launch_bounds__(256) void k_cvt_one(const float* __restrict__ src, u16* __restrict__ dst){
  int t = blockIdx.x;                 // 24*24 tiles for 1536x1536
  cvt_tile(src, 1536, 1536, dst, (t/24)<<6, (t%24)<<6, 0, 0);
}

// ---------------- GEMM: C(4096xN) = A(4096xK)bf16 * Bt(NxK)bf16^T  (m97-style 128^2 tile) ----------------
#define MODE_QKV 0
#define MODE_WO 1
#define MODE_GATEUP 2
#define MODE_DOWN 3
#define MODE_W1 4

template<int MODE>
__global__ __launch_bounds__(256) void k_gemm(
  const u16* __restrict__ A, const u16* __restrict__ Bt, int K,
  const float* __restrict__ bq_, const float* __restrict__ bk_, const float* __restrict__ bv_,
  float* __restrict__ xio, u16* __restrict__ o0, u16* __restrict__ o1, u16* __restrict__ o2)
{
  __shared__ u16 As[4096], Bs[4096];      // [kb(4)][row(128)][8] bf16 granules
  int tid = threadIdx.x;
  int lane = tid & 63, w = tid >> 6;
  int wr = w >> 1, wc = w & 1;
  int row0 = blockIdx.y * 128, col0 = blockIdx.x * 128;
  int l15 = lane & 15, l4 = lane >> 4;
  f32x4 acc[4][4] = {};
  const u16* aBase = A + (size_t)row0*K;
  const u16* bBase = Bt + (size_t)col0*K;
  int rr0 = tid & 127, kb0 = tid >> 7;          // granule (ld=0)
  int kb1 = kb0 + 2;                            // granule (ld=1): g=256+tid
  for (int kt = 0; kt < K; kt += 32){
    gld16(aBase + (size_t)rr0*K + kt + kb0*8, &As[tid*8]);
    gld16(bBase + (size_t)rr0*K + kt + kb0*8, &Bs[tid*8]);
    gld16(aBase + (size_t)rr0*K + kt + kb1*8, &As[(256+tid)*8]);
    gld16(bBase + (size_t)rr0*K + kt + kb1*8, &Bs[(256+tid)*8]);
    __syncthreads();
    s16x8 af[4], bf_[4];
    #pragma unroll
    for (int i=0;i<4;++i) af[i]  = *(const s16x8*)&As[((l4<<7) + wr*64 + i*16 + l15)*8];
    #pragma unroll
    for (int j=0;j<4;++j) bf_[j] = *(const s16x8*)&Bs[((l4<<7) + wc*64 + j*16 + l15)*8];
    #pragma unroll
    for (int i=0;i<4;++i)
      #pragma unroll
      for (int j=0;j<4;++j)
        acc[i][j] = __builtin_amdgcn_mfma_f32_16x16x32_bf16(af[i], bf_[j], acc[i][j], 0, 0, 0);
    __syncthreads();
  }
  if constexpr (MODE == MODE_GATEUP){
    #pragma unroll
    for (int i=0;i<4;++i)
      #pragma unroll
      for (int j2=0;j2<4;j2+=2)
        #pragma unroll
        for (int r=0;r<4;++r){
          int row = row0 + wr*64 + i*16 + l4*4 + r;
          int cp  = col0 + wc*64 + j2*16 + l15;
          float gv = acc[i][j2][r], uv = acc[i][j2+1][r];
          float sg = 1.f/(1.f + __expf(-gv));
          int n = ((cp>>5)<<4) + (cp&15);
          o0[(size_t)row*8960 + n] = f2bf(sg*uv);
        }
  } else {
    #pragma unroll
    for (int i=0;i<4;++i)
      #pragma unroll
      for (int j=0;j<4;++j)
        #pragma unroll
        for (int r=0;r<4;++r){
          int row = row0 + wr*64 + i*16 + l4*4 + r;
          int c   = col0 + wc*64 + j*16 + l15;
          float v = acc[i][j][r];
          if constexpr (MODE == MODE_QKV){
            int bb = row >> 11, s = row & 2047;
            if (c < 1536){
              v += bq_[c];
              int hd = c >> 6, d = c & 63;
              o0[(((size_t)(bb*24 + hd)*2048 + s)<<6) + d] = f2bf(v);
            } else if (c < 1792){
              int c2 = c - 1536; v += bk_[c2];
              int hd = c2 >> 6, d = c2 & 63;
              o1[(((size_t)(bb*4 + hd)*2048 + s)<<6) + d] = f2bf(v);
            } else {
              int c2 = c - 1792; v += bv_[c2];
              int hd = c2 >> 6, d = c2 & 63;
              o2[(((size_t)(bb*4 + hd)*2048 + s)<<6) + d] = f2bf(v);
            }
          } else if constexpr (MODE == MODE_WO || MODE == MODE_DOWN){
            xio[(size_t)row*1536 + c] += v;
          } else { // MODE_W1: exact gelu
            v += bq_[c];
            float ge = 0.5f * v * (1.f + erff(v * 0.70710678118f));
            o0[(size_t)row*1536 + c] = f2bf(ge);
          }
        }
  }
}

// ---------------- flash attention, bf16 MFMA, fixed-offset softmax ----------------
#define MFIX 4.0f
__global__ __launch_bounds__(256) void k_attn(
  const u16* __restrict__ q, const u16* __restrict__ k, const u16* __restrict__ v,
  const float* __restrict__ mask, const float* __restrict__ cosT, const float* __restrict__ sinT,
  u16* __restrict__ attn)
{
  __shared__ u16 Qs[4096];   // [kb8][row64][8]
  __shared__ u16 Ks[2048];   // [kb8][row32][8]
  __shared__ u16 Vt[2048];   // [kkb4][d64][8]
  __shared__ u16 Ps[4*512];  // per wave [kkb4][q16][8]
  __shared__ float Ms[32];
  int tid = threadIdx.x;
  int lane = tid & 63, w = tid >> 6;
  int qb = blockIdx.x;        // 0..31
  int bh = blockIdx.y;        // 0..47
  int b = bh / 24, hh = bh % 24, kv = hh / 6;
  int l15 = lane & 15, l4 = lane >> 4;

  const u16* qhead = q + (((size_t)(b*24 + hh)) << 17);
  const u16* khead = k + (((size_t)(b*4  + kv)) << 17);
  const u16* vhead = v + (((size_t)(b*4  + kv)) << 17);

  // stage Q with rope, pre-scaled by 1/sqrt(64)
  #pragma unroll
  for (int ld = 0; ld < 2; ++ld){
    int g = ld*256 + tid;
    int row = g & 63, kb = g >> 6;
    int s = qb*64 + row;
    const u16* qr = qhead + ((size_t)s << 6);
    u16x8 a = *(const u16x8*)(qr + kb*8);
    u16x8 p = *(const u16x8*)(qr + (kb^4)*8);
    const float* cg = cosT + s*64 + kb*8;
    const float* sg = sinT + s*64 + kb*8;
    float sgn = (kb < 4) ? -1.f : 1.f;
    u16x8 o;
    #pragma unroll
    for (int m=0;m<8;++m){
      float val = bf2f(a[m])*cg[m] + sgn*bf2f(p[m])*sg[m];
      o[m] = f2bf(val * 0.125f);
    }
    *(u16x8*)&Qs[g*8] = o;
  }
  __syncthreads();
  s16x8 aq0 = *(const s16x8*)&Qs[(( l4   *64) + w*16 + l15)*8];
  s16x8 aq1 = *(const s16x8*)&Qs[(((4+l4)*64) + w*16 + l15)*8];
  f32x4 oacc[4] = {};
  float lsum[4] = {0.f,0.f,0.f,0.f};

  for (int kt = 0; kt < 64; ++kt){
    __syncthreads();
    {
      int g = tid;
      int row = g & 31, kb = g >> 5;
      int s = kt*32 + row;
      const u16* kr = khead + ((size_t)s << 6);
      u16x8 a = *(const u16x8*)(kr + kb*8);
      u16x8 p = *(const u16x8*)(kr + (kb^4)*8);
      const float* cg = cosT + s*64 + kb*8;
      const float* sg = sinT + s*64 + kb*8;
      float sgn = (kb < 4) ? -1.f : 1.f;
      u16x8 o;
      #pragma unroll
      for (int m=0;m<8;++m) o[m] = f2bf(bf2f(a[m])*cg[m] + sgn*bf2f(p[m])*sg[m]);
      *(u16x8*)&Ks[g*8] = o;
      // V transposed into Vt
      const u16* vr = vhead + ((size_t)s << 6);
      u16x8 vv = *(const u16x8*)(vr + kb*8);
      int kkb = row >> 3, e = row & 7;
      #pragma unroll
      for (int m=0;m<8;++m) Vt[(kkb*64 + kb*8 + m)*8 + e] = vv[m];
      if (tid < 32) Ms[tid] = (mask[b*2048 + kt*32 + tid] == 0.f) ? -1e9f : 0.f;
    }
    __syncthreads();
    f32x4 s0 = {0,0,0,0}, s1 = {0,0,0,0};
    s16x8 b00 = *(const s16x8*)&Ks[(( l4   *32)      + l15)*8];
    s16x8 b01 = *(const s16x8*)&Ks[(( l4   *32) + 16 + l15)*8];
    s16x8 b10 = *(const s16x8*)&Ks[(((4+l4)*32)      + l15)*8];
    s16x8 b11 = *(const s16x8*)&Ks[(((4+l4)*32) + 16 + l15)*8];
    s0 = __builtin_amdgcn_mfma_f32_16x16x32_bf16(aq0, b00, s0, 0,0,0);
    s0 = __builtin_amdgcn_mfma_f32_16x16x32_bf16(aq1, b10, s0, 0,0,0);
    s1 = __builtin_amdgcn_mfma_f32_16x16x32_bf16(aq0, b01, s1, 0,0,0);
    s1 = __builtin_amdgcn_mfma_f32_16x16x32_bf16(aq1, b11, s1, 0,0,0);
    float mb0 = Ms[l15], mb1 = Ms[16+l15];
    u16* Pw = &Ps[w*512];
    #pragma unroll
    for (int r=0;r<4;++r){
      float p0 = __expf(s0[r] + mb0 - MFIX);
      float p1 = __expf(s1[r] + mb1 - MFIX);
      lsum[r] += p0 + p1;
      int qq = l4*4 + r;
      Pw[(( (l15>>3)    )*16 + qq)*8 + (l15&7)] = f2bf(p0);
      Pw[(( 2+(l15>>3)  )*16 + qq)*8 + (l15&7)] = f2bf(p1);
    }
    s16x8 ap = *(const s16x8*)&Pw[(l4*16 + l15)*8];
    #pragma unroll
    for (int dg=0;dg<4;++dg){
      s16x8 bv = *(const s16x8*)&Vt[((l4*64) + dg*16 + l15)*8];
      oacc[dg] = __builtin_amdgcn_mfma_f32_16x16x32_bf16(ap, bv, oacc[dg], 0,0,0);
    }
  }
  #pragma unroll
  for (int r=0;r<4;++r){
    float t = lsum[r];
    t += __shfl_xor(t, 1, 64); t += __shfl_xor(t, 2, 64);
    t += __shfl_xor(t, 4, 64); t += __shfl_xor(t, 8, 64);
    lsum[r] = 1.f / t;
  }
  #pragma unroll
  for (int dg=0;dg<4;++dg)
    #pragma unroll
    for (int r=0;r<4;++r){
      int token = b*2048 + qb*64 + w*16 + l4*4 + r;
      int col = hh*64 + dg*16 + l15;
      attn[(size_t)token*1536 + col] = f2bf(oacc[dg][r] * lsum[r]);
    }
}

// ---------------- final GEMV: out[r] = h2[r,:] . W2 + b2 ----------------
__global__ __launch_bounds__(256) void k_gemv(const u16* __restrict__ h2, const float* __restrict__ W2, const float* __restrict__ b2, float* __restrict__ out){
  int tid = threadIdx.x, lane = tid & 63, w = tid >> 6;
  int r = blockIdx.x*4 + w;
  const u16* hr = h2 + (size_t)r*1536;
  float s = 0.f;
  #pragma unroll
  for (int i=0;i<24;++i){ int c = lane + i*64; s += bf2f(hr[c]) * W2[c]; }
  #pragma unroll
  for (int off=32; off; off>>=1) s += __shfl_xor(s, off, 64);
  if (lane == 0) out[r] = s + b2[0];
}

extern "C" void kernel_launch(void* const* d_in, const int* in_sizes, int n_in,
                              void* d_out, int out_size, void* d_ws, size_t ws_size,
                              hipStream_t stream)
{
  const int*   ids   = (const int*)d_in[0];
  const float* mask  = (const float*)d_in[1];
  const float* embed = (const float*)d_in[2];
  const float* Wq    = (const float*)d_in[3];
  const float* bq    = (const float*)d_in[4];
  const float* Wk    = (const float*)d_in[5];
  const float* bk    = (const float*)d_in[6];
  const float* Wv    = (const float*)d_in[7];
  const float* bv    = (const float*)d_in[8];
  const float* Wo    = (const float*)d_in[9];
  const float* ln1   = (const float*)d_in[10];
  const float* ln2   = (const float*)d_in[11];
  const float* Wg    = (const float*)d_in[12];
  const float* Wu    = (const float*)d_in[13];
  const float* Wd    = (const float*)d_in[14];
  const float* nw    = (const float*)d_in[15];
  const float* W1    = (const float*)d_in[16];
  const float* b1    = (const float*)d_in[17];
  const float* W2    = (const float*)d_in[18];
  const float* b2    = (const float*)d_in[19];
  const float* cosT  = (const float*)d_in[20];
  const float* sinT  = (const float*)d_in[21];

  // workspace layout (bytes); total ~223.3 MiB
  char* ws = (char*)d_ws;
  float* x   = (float*)(ws + 0);            // 4096x1536 f32
  u16* h     = (u16*)(ws + 25165824);       // 4096x1536 bf16
  u16* qb_   = (u16*)(ws + 37748736);       // (2,24,2048,64) bf16
  u16* kb_   = (u16*)(ws + 50331648);       // (2,4,2048,64) bf16
  u16* vb_   = (u16*)(ws + 52428800);       // (2,4,2048,64) bf16
  u16* attn  = (u16*)(ws + 54525952);       // 4096x1536 bf16 (also final gelu h2)
  u16* g     = (u16*)(ws + 67108864);       // 4096x8960 bf16
  u16* qkvt  = (u16*)(ws + 140509184);      // 2048x1536 bf16
  u16* wot   = (u16*)(ws + 146800640);      // 1536x1536 bf16
  u16* gut   = (u16*)(ws + 151519232);      // 17920x1536 bf16
  u16* wdt   = (u16*)(ws + 206569472);      // 1536x8960 bf16
  (void)in_sizes; (void)n_in; (void)out_size; (void)ws_size;

  k_embed<<<4096, 256, 0, stream>>>(ids, embed, x);
  for (int l = 0; l < 8; ++l){
    k_cvt_layer<<<dim3(3360,7), 256, 0, stream>>>(
      Wq + (size_t)l*1536*1536, Wk + (size_t)l*1536*256, Wv + (size_t)l*1536*256,
      Wo + (size_t)l*1536*1536, Wg + (size_t)l*1536*8960, Wu + (size_t)l*1536*8960,
      Wd + (size_t)l*8960*1536, qkvt, wot, gut, wdt);
    k_rms<<<4096, 256, 0, stream>>>(x, ln1 + l*1536, h);
    k_gemm<MODE_QKV><<<dim3(16,32), 256, 0, stream>>>(h, qkvt, 1536,
        bq + l*1536, bk + l*256, bv + l*256, nullptr, qb_, kb_, vb_);
    k_attn<<<dim3(32,48), 256, 0, stream>>>(qb_, kb_, vb_, mask, cosT, sinT, attn);
    k_gemm<MODE_WO><<<dim3(12,32), 256, 0, stream>>>(attn, wot, 1536,
        nullptr, nullptr, nullptr, x, nullptr, nullptr, nullptr);
    k_rms<<<4096, 256, 0, stream>>>(x, ln2 + l*1536, h);
    k_gemm<MODE_GATEUP><<<dim3(140,32), 256, 0, stream>>>(h, gut, 1536,
        nullptr, nullptr, nullptr, nullptr, g, nullptr, nullptr);
    k_gemm<MODE_DOWN><<<dim3(12,32), 256, 0, stream>>>(g, wdt, 8960,
        nullptr, nullptr, nullptr, x, nullptr, nullptr, nullptr);
  }
  k_cvt_one<<<576, 256, 0, stream>>>(W1, wot);
  k_rms<<<4096, 256, 0, stream>>>(x, nw, h);
  k_gemm<MODE_W1><<<dim3(12,32), 256, 0, stream>>>(h, wot, 1536,
      b1, nullptr, nullptr, nullptr, attn, nullptr, nullptr);
  k_gemv<<<1024, 256, 0, stream>>>(attn, W2, b2, (float*)d_out);
}